// Round 10
// baseline (14625.830 us; speedup 1.0000x reference)
//
#include <hip/hip_runtime.h>
#include <cstdint>
#include <cstddef>

#define U4    512   // 4*U
#define UNITS 128
#define BATCH 256
#define TSEQ  512
#define FEAT  64

typedef short short8 __attribute__((ext_vector_type(8)));
typedef float f32x4  __attribute__((ext_vector_type(4)));

// ---------------- fast activations (fp32, ~1e-7 rel err) ----------------
__device__ __forceinline__ float sigm(float x) {
    float e = __expf(-x);
    return __fdividef(1.0f, 1.0f + e);
}
__device__ __forceinline__ float tanh_fast(float x) {
    float e = __expf(2.0f * x);
    return 1.0f - __fdividef(2.0f, e + 1.0f);
}

// ---------------- bf16 split helpers (RNE) ----------------
__device__ __forceinline__ unsigned short f2bf(float f) {
    unsigned u = __float_as_uint(f);
    unsigned r = u + 0x7FFFu + ((u >> 16) & 1u);
    return (unsigned short)(r >> 16);
}
__device__ __forceinline__ float bf2f(unsigned short h) {
    return __uint_as_float(((unsigned)h) << 16);
}

// ---------------- x -> bf16 hi/lo split, per (b,t): [hi64 | lo64] shorts ----
__global__ __launch_bounds__(256)
void x_prep(const float* __restrict__ x, unsigned short* __restrict__ xs)
{
    int gid = blockIdx.x * 256 + threadIdx.x;   // 256*512*8
    int bt = gid >> 3, j8 = gid & 7;
    const float* p = x + (size_t)bt * 64 + j8 * 8;
    float4 a = *(const float4*)p;
    float4 b = *(const float4*)(p + 4);
    float v[8] = {a.x, a.y, a.z, a.w, b.x, b.y, b.z, b.w};
    short8 hi, lo;
    #pragma unroll
    for (int j = 0; j < 8; ++j) {
        unsigned short h = f2bf(v[j]);
        hi[j] = (short)h;
        lo[j] = (short)f2bf(v[j] - bf2f(h));
    }
    *(short8*)(xs + (size_t)bt * 128 + j8 * 8)      = hi;
    *(short8*)(xs + (size_t)bt * 128 + 64 + j8 * 8) = lo;
}

// ---------------- weights -> bf16 hi/lo MFMA B-fragments ----------------
// B-layout (validated R7-R9): lane holds B[k=kt*32+(lane>>4)*8+j][n=nt*16+(lane&15)].
// Region layout (short8 units of 8 shorts): [R0|R1|R2|W1|W2](16384 units each, kt=4)[W0](8192, kt=2)
__global__ __launch_bounds__(256)
void w_frag(const float* __restrict__ R0, const float* __restrict__ R1,
            const float* __restrict__ R2, const float* __restrict__ W1,
            const float* __restrict__ W2, const float* __restrict__ W0,
            unsigned short* __restrict__ out)
{
    int gid = blockIdx.x * 256 + threadIdx.x;    // 90112
    if (gid >= 90112) return;
    const float* M; int idx; int nkt = 4;
    if      (gid < 16384) { M = R0; idx = gid; }
    else if (gid < 32768) { M = R1; idx = gid - 16384; }
    else if (gid < 49152) { M = R2; idx = gid - 32768; }
    else if (gid < 65536) { M = W1; idx = gid - 49152; }
    else if (gid < 81920) { M = W2; idx = gid - 65536; }
    else                  { M = W0; idx = gid - 81920; nkt = 2; }
    int lane = idx & 63;
    int pass = (idx >> 6) & 1;
    int u2   = idx >> 7;                  // nt*nkt + kt
    int kt   = u2 & (nkt - 1);
    int nt   = (nkt == 4) ? (u2 >> 2) : (u2 >> 1);
    int n  = nt * 16 + (lane & 15);
    int k0 = kt * 32 + (lane >> 4) * 8;
    short8 v;
    #pragma unroll
    for (int j = 0; j < 8; ++j) {
        float xv = M[(size_t)(k0 + j) * U4 + n];
        unsigned short h = f2bf(xv);
        unsigned short s = pass ? f2bf(xv - bf2f(h)) : h;
        v[j] = (short)s;
    }
    *(short8*)(out + (size_t)gid * 8) = v;
}

template<int NKT>
__device__ __forceinline__ void mfma_chain(const short8 (&a_)[4],
                                           const short8 (&bfr)[4][4][2],
                                           f32x4 (&C)[4], f32x4 zc)
{
    // first link consumes the persistent zero-C (no per-step accvgpr zeroing)
    #pragma unroll
    for (int j = 0; j < 4; ++j)
        C[j] = __builtin_amdgcn_mfma_f32_16x16x32_bf16(a_[0], bfr[j][0][0], zc, 0, 0, 0);
    #pragma unroll
    for (int kt = 1; kt < NKT; ++kt)
        #pragma unroll
        for (int j = 0; j < 4; ++j)
            C[j] = __builtin_amdgcn_mfma_f32_16x16x32_bf16(a_[kt], bfr[j][kt][0], C[j], 0, 0, 0);
    #pragma unroll
    for (int kt = 0; kt < NKT; ++kt)
        #pragma unroll
        for (int j = 0; j < 4; ++j)
            C[j] = __builtin_amdgcn_mfma_f32_16x16x32_bf16(a_[kt], bfr[j][kt][1], C[j], 0, 0, 0);
}

// ---------------- fully-fused LSTM layer (recurrence + input projection) ----
// 1 block/seq, 1024 threads = 16 waves. Wave = (ng = w>>1 : cols [ng*64,+64))
// x (team = w&1): team 0 computes h_{t-1}@R (A rows 0/1 = h hi/lo from LDS
// htab), team 1 computes hprev_t@W (A rows 0/1 = prev-layer h hi/lo,
// PREFETCHED from global one step ahead -> vmcnt-hidden; hprev is not
// recurrent). Partials meet in abuf[col][team]; phase B (tid<128) adds
// bias (preloaded regs) + activations + c/h update. This replaces
// proj_gemm entirely: xw (67MB/dispatch) -> 512B/step hprev reads.
// 2 barriers/step; htab/abuf single-buffered (producer/consumer strictly
// alternates across the barriers, R9-validated).
template<int NKTW>
__global__ __launch_bounds__(1024)
void lstm_rec(const unsigned short* __restrict__ prev, int bStride, int tStride, int loOff,
              const unsigned short* __restrict__ Rf, const unsigned short* __restrict__ Wf,
              const float* __restrict__ bias,
              float* __restrict__ h_state, float* __restrict__ c_state,
              unsigned short* __restrict__ h_out, int hoBStride,
              int Tc, int init)
{
    const int tid  = threadIdx.x;
    const int b    = blockIdx.x;
    const int lane = tid & 63;
    const int w    = tid >> 6;       // 0..15
    const int ng   = w >> 1;         // 0..7: cols [ng*64, +64)
    const int isW  = w & 1;          // team: 0 = R-half, 1 = W-half
    const int m    = lane & 15;
    const int quad = lane >> 4;

    __shared__ __align__(16) unsigned short htab[2][136];  // row0 = h_hi, row1 = h_lo
    __shared__ __align__(8)  float abuf[U4][2];            // [gate][team]

    // B fragments -> AGPRs (MFMA reads them natively)
    short8 bfr[4][4][2];
    if (!isW) {
        #pragma unroll
        for (int nt = 0; nt < 4; ++nt)
            #pragma unroll
            for (int kt = 0; kt < 4; ++kt)
                #pragma unroll
                for (int pp = 0; pp < 2; ++pp)
                    bfr[nt][kt][pp] = *(const short8*)(
                        Rf + ((size_t)(((ng * 4 + nt) * 4 + kt) * 2 + pp) * 64 + lane) * 8);
    } else {
        #pragma unroll
        for (int nt = 0; nt < 4; ++nt)
            #pragma unroll
            for (int kt = 0; kt < NKTW; ++kt)
                #pragma unroll
                for (int pp = 0; pp < 2; ++pp)
                    bfr[nt][kt][pp] = *(const short8*)(
                        Wf + ((size_t)(((ng * 4 + nt) * NKTW + kt) * 2 + pp) * 64 + lane) * 8);
    }

    const int u = tid & 127;
    float c = 0.f, hcur = 0.f;
    float bi = 0.f, bff = 0.f, bg = 0.f, bo = 0.f;
    if (tid < 128) {
        if (!init) {
            hcur = h_state[b * UNITS + u];
            c    = c_state[b * UNITS + u];
        }
        unsigned short hi = f2bf(hcur);
        htab[0][u] = hi;
        htab[1][u] = f2bf(hcur - bf2f(hi));
        bi  = bias[u];
        bff = bias[128 + u];
        bg  = bias[256 + u];
        bo  = bias[384 + u];
    }

    const unsigned short* pB = prev + (size_t)b * bStride;
    unsigned short* hoB = h_out ? (h_out + (size_t)b * hoBStride) : nullptr;

    // A-frag registers: lanes m>=2 stay zero forever (masked loads only touch m<2)
    short8 afA[4] = {}, afB[4] = {};
    if (isW && m < 2) {
        const unsigned short* pt = pB + m * loOff;   // t = 0
        #pragma unroll
        for (int kt = 0; kt < NKTW; ++kt)
            afA[kt] = *(const short8*)(pt + kt * 32 + quad * 8);
    }
    __syncthreads();

    const f32x4 zc = {0.f, 0.f, 0.f, 0.f};
    const int col0 = ng * 64 + m;

    auto step = [&](int t, short8 (&afu)[4], short8 (&afl)[4]) {
        // W-team: prefetch t+1's hprev fragment (hidden under MFMA+phaseB)
        if (isW && m < 2) {
            int tn = (t + 1 < Tc) ? t + 1 : t;
            const unsigned short* pt = pB + (size_t)tn * tStride + m * loOff;
            #pragma unroll
            for (int kt = 0; kt < NKTW; ++kt)
                afl[kt] = *(const short8*)(pt + kt * 32 + quad * 8);
        }
        // R-team: A-frags from htab (h_{t-1}, written by phase B of t-1)
        if (!isW && m < 2) {
            #pragma unroll
            for (int kt = 0; kt < 4; ++kt)
                afu[kt] = *(const short8*)(&htab[m][kt * 32 + quad * 8]);
        }

        f32x4 C[4];
        if (!isW) mfma_chain<4>(afu, bfr, C, zc);
        else      mfma_chain<NKTW>(afu, bfr, C, zc);

        if (quad == 0) {   // rows 0/1 live in quad-0 lanes, regs .x/.y
            abuf[col0     ][isW] = C[0].x + C[0].y;
            abuf[col0 + 16][isW] = C[1].x + C[1].y;
            abuf[col0 + 32][isW] = C[2].x + C[2].y;
            abuf[col0 + 48][isW] = C[3].x + C[3].y;
        }
        __syncthreads();   // barrier 1: abuf complete

        if (tid < 128) {
            float2 pi = *(const float2*)&abuf[u][0];
            float2 pf = *(const float2*)&abuf[u + 128][0];
            float2 pg = *(const float2*)&abuf[u + 256][0];
            float2 po = *(const float2*)&abuf[u + 384][0];
            float iv = sigm(pi.x + pi.y + bi);
            float fv = sigm(pf.x + pf.y + bff);
            float gv = tanh_fast(pg.x + pg.y + bg);
            float ov = sigm(po.x + po.y + bo);
            c = __builtin_fmaf(fv, c, iv * gv);
            hcur = ov * tanh_fast(c);
            unsigned short hi = f2bf(hcur);
            unsigned short lo = f2bf(hcur - bf2f(hi));
            htab[0][u] = hi;
            htab[1][u] = lo;
            if (hoB) {
                hoB[(size_t)t * 256 + u]       = hi;
                hoB[(size_t)t * 256 + 128 + u] = lo;
            }
        }
        __syncthreads();   // barrier 2: htab ready for t+1
    };

    #pragma unroll 1
    for (int t = 0; t < Tc; t += 2) {
        step(t,     afA, afB);
        step(t + 1, afB, afA);
    }

    if (tid < 128) {
        h_state[b * UNITS + u] = hcur;
        c_state[b * UNITS + u] = c;
    }
}

// ---------------- dense head ----------------
__global__ __launch_bounds__(256)
void dense_head(const float* __restrict__ h2, const float* __restrict__ Wd,
                const float* __restrict__ bd, float* __restrict__ out)
{
    int b = threadIdx.x;
    float acc[6];
    #pragma unroll
    for (int o = 0; o < 6; ++o) acc[o] = bd[o];
    #pragma unroll 4
    for (int k = 0; k < UNITS; ++k) {
        float hv = h2[b * UNITS + k];
        #pragma unroll
        for (int o = 0; o < 6; ++o)
            acc[o] = __builtin_fmaf(hv, Wd[k * 6 + o], acc[o]);
    }
    #pragma unroll
    for (int o = 0; o < 6; ++o) out[b * 6 + o] = acc[o];
}

extern "C" void kernel_launch(void* const* d_in, const int* in_sizes, int n_in,
                              void* d_out, int out_size, void* d_ws, size_t ws_size,
                              hipStream_t stream)
{
    (void)in_sizes; (void)n_in; (void)out_size;
    const float* x  = (const float*)d_in[0];
    const float* W0 = (const float*)d_in[1];
    const float* R0 = (const float*)d_in[2];
    const float* b0 = (const float*)d_in[3];
    const float* W1 = (const float*)d_in[4];
    const float* R1 = (const float*)d_in[5];
    const float* b1 = (const float*)d_in[6];
    const float* W2 = (const float*)d_in[7];
    const float* R2 = (const float*)d_in[8];
    const float* b2 = (const float*)d_in[9];
    const float* Wd = (const float*)d_in[10];
    const float* bd = (const float*)d_in[11];
    float* out = (float*)d_out;

    // ws layout (shorts): xs[16777216] | frags[720896] | hbufA | hbufB | states(f32)
    // bytes: 33,554,432 + 1,441,792 + 2*Tc*131072 + 786,432
    int Tc = 512;
    while (Tc > 64) {
        size_t need = 35782656ull + (size_t)Tc * 262144ull;
        if (need <= ws_size) break;
        Tc >>= 1;
    }
    const int nCh = TSEQ / Tc;

    unsigned short* xs   = (unsigned short*)d_ws;
    unsigned short* frag = xs + 16777216;
    unsigned short* hbufA = frag + 720896;
    unsigned short* hbufB = hbufA + (size_t)Tc * 65536;   // 256 b * Tc * 256 shorts
    float* hs = (float*)(hbufB + (size_t)Tc * 65536);     // 3 x [256][128]
    float* cs = hs + 3 * BATCH * UNITS;

    unsigned short* fR0 = frag;
    unsigned short* fR1 = frag + 131072;
    unsigned short* fR2 = frag + 262144;
    unsigned short* fW1 = frag + 393216;
    unsigned short* fW2 = frag + 524288;
    unsigned short* fW0 = frag + 655360;

    x_prep<<<4096, 256, 0, stream>>>(x, xs);
    w_frag<<<352, 256, 0, stream>>>(R0, R1, R2, W1, W2, W0, frag);

    for (int ch = 0; ch < nCh; ++ch) {
        const int t0 = ch * Tc;
        const int init = (ch == 0) ? 1 : 0;
        // layer 0: prev = x-split (full-T layout), K_W = 64 -> NKTW = 2
        lstm_rec<2><<<BATCH, 1024, 0, stream>>>(
            xs + (size_t)t0 * 128, TSEQ * 128, 128, 64,
            fR0, fW0, b0, hs + 0 * BATCH * UNITS, cs + 0 * BATCH * UNITS,
            hbufA, Tc * 256, Tc, init);
        // layer 1: prev = layer0 h (chunk buffer), K_W = 128
        lstm_rec<4><<<BATCH, 1024, 0, stream>>>(
            hbufA, Tc * 256, 256, 128,
            fR1, fW1, b1, hs + 1 * BATCH * UNITS, cs + 1 * BATCH * UNITS,
            hbufB, Tc * 256, Tc, init);
        // layer 2: prev = layer1 h; no per-step output (return_sequences=False)
        lstm_rec<4><<<BATCH, 1024, 0, stream>>>(
            hbufB, Tc * 256, 256, 128,
            fR2, fW2, b2, hs + 2 * BATCH * UNITS, cs + 2 * BATCH * UNITS,
            nullptr, 0, Tc, init);
    }
    dense_head<<<1, 256, 0, stream>>>(hs + 2 * BATCH * UNITS, Wd, bd, out);
}